// Round 2
// baseline (265.718 us; speedup 1.0000x reference)
//
#include <hip/hip_runtime.h>

#define DIM 2048

typedef unsigned int uint2v __attribute__((ext_vector_type(2)));

// Exact sign flip: signs are +/-1 int32; -1 has the int sign bit set.
__device__ __forceinline__ float4 sign_flip(float4 v, uint4 s) {
  float4 r;
  r.x = __uint_as_float(__float_as_uint(v.x) ^ (s.x & 0x80000000u));
  r.y = __uint_as_float(__float_as_uint(v.y) ^ (s.y & 0x80000000u));
  r.z = __uint_as_float(__float_as_uint(v.z) ^ (s.z & 0x80000000u));
  r.w = __uint_as_float(__float_as_uint(v.w) ^ (s.w & 0x80000000u));
  return r;
}

#define BFLY(a, b) { float _t = (a); (a) = _t + (b); (b) = _t - (b); }

__device__ __forceinline__ void bf4_pair(float4 &a, float4 &b) {
  BFLY(a.x, b.x); BFLY(a.y, b.y); BFLY(a.z, b.z); BFLY(a.w, b.w);
}

// Butterfly element-index bits 0 and 1 (within the float4 components).
__device__ __forceinline__ void bf_comps(float4 &a) {
  BFLY(a.x, a.y); BFLY(a.z, a.w);   // bit 0
  BFLY(a.x, a.z); BFLY(a.y, a.w);   // bit 1
}

// Butterfly the 3 bits of the 8-register index (strides 1,2,4).
__device__ __forceinline__ void bf_oct(float4 v[8]) {
  bf4_pair(v[0], v[1]); bf4_pair(v[2], v[3]);
  bf4_pair(v[4], v[5]); bf4_pair(v[6], v[7]);
  bf4_pair(v[0], v[2]); bf4_pair(v[1], v[3]);
  bf4_pair(v[4], v[6]); bf4_pair(v[5], v[7]);
  bf4_pair(v[0], v[4]); bf4_pair(v[1], v[5]);
  bf4_pair(v[2], v[6]); bf4_pair(v[3], v[7]);
}

// Cross-lane butterfly on lane bit 0 / 1 via DPP quad_perm (VALU rate).
// 0xB1 = [1,0,3,2] (xor1), 0x4E = [2,3,0,1] (xor2).
template <int CTRL>
__device__ __forceinline__ float dpp_mov(float x) {
  return __int_as_float(
      __builtin_amdgcn_mov_dpp(__float_as_int(x), CTRL, 0xF, 0xF, true));
}

template <int CTRL>
__device__ __forceinline__ void dpp_stage(float4 v[8], float sgn) {
  #pragma unroll
  for (int i = 0; i < 8; ++i) {
    float px = dpp_mov<CTRL>(v[i].x);
    float py = dpp_mov<CTRL>(v[i].y);
    float pz = dpp_mov<CTRL>(v[i].z);
    float pw = dpp_mov<CTRL>(v[i].w);
    // lane with bit clear: x + partner ; lane with bit set: partner - x
    v[i].x = fmaf(sgn, v[i].x, px);
    v[i].y = fmaf(sgn, v[i].y, py);
    v[i].z = fmaf(sgn, v[i].z, pz);
    v[i].w = fmaf(sgn, v[i].w, pw);
  }
}

// Cross-lane butterfly on lane bits 2..4 via ds_swizzle bit-mode xor.
// Pattern = (xor<<10) | (0x1F and-mask): pure lane^xor within 32-lane
// groups. Uses the DS crossbar only — no LDS storage, no bank conflicts,
// no barriers; lgkmcnt dependencies are tracked by the compiler.
template <int PAT>
__device__ __forceinline__ float swz_mov(float x) {
  return __int_as_float(__builtin_amdgcn_ds_swizzle(__float_as_int(x), PAT));
}

template <int PAT>
__device__ __forceinline__ void swz_stage(float4 v[8], float sgn) {
  #pragma unroll
  for (int i = 0; i < 8; ++i) {
    float px = swz_mov<PAT>(v[i].x);
    float py = swz_mov<PAT>(v[i].y);
    float pz = swz_mov<PAT>(v[i].z);
    float pw = swz_mov<PAT>(v[i].w);
    v[i].x = fmaf(sgn, v[i].x, px);
    v[i].y = fmaf(sgn, v[i].y, py);
    v[i].z = fmaf(sgn, v[i].z, pz);
    v[i].w = fmaf(sgn, v[i].w, pw);
  }
}

// Cross-lane butterfly on lane bit 5 via v_permlane32_swap_b32 (VALU rate).
// permlane32_swap(x, x) returns r[0] = x[lane & ~32] (lo half duplicated)
// and r[1] = x[lane | 32] (hi half duplicated).
__device__ __forceinline__ float pl32_bfly(float x, float sgn) {
  uint2v r = __builtin_amdgcn_permlane32_swap(
      __float_as_uint(x), __float_as_uint(x), false, false);
  // out = x[clear] + sgn * x[set]:
  //   lane<32: x[l] + x[l+32] ; lane>=32: x[l-32] - x[l]
  return fmaf(sgn, __uint_as_float(r[1]), __uint_as_float(r[0]));
}

__device__ __forceinline__ void pl32_stage(float4 v[8], float sgn) {
  #pragma unroll
  for (int i = 0; i < 8; ++i) {
    v[i].x = pl32_bfly(v[i].x, sgn);
    v[i].y = pl32_bfly(v[i].y, sgn);
    v[i].z = pl32_bfly(v[i].z, sgn);
    v[i].w = pl32_bfly(v[i].w, sgn);
  }
}

// One wave per 2048-float row, everything in home position — NO LDS,
// NO barriers, NO transposes. Element index e = c*256 + lane*4 + comp:
//   bits 0-1: float4 comps   (bf_comps)
//   bit  2  : lane^1         (DPP quad_perm 0xB1)
//   bit  3  : lane^2         (DPP quad_perm 0x4E)
//   bit  4  : lane^4         (ds_swizzle 0x101F)
//   bit  5  : lane^8         (ds_swizzle 0x201F)
//   bit  6  : lane^16        (ds_swizzle 0x401F)
//   bit  7  : lane^32        (permlane32_swap)
//   bits 8-10: reg index c   (bf_oct)
// FWHT stages act on disjoint tensor factors, so any bit order is exact.
__global__ __launch_bounds__(256, 8) void srht2_kernel(
    const float* __restrict__ x, const int* __restrict__ signs,
    float* __restrict__ out, int nrows) {
  const int lane = threadIdx.x & 63;
  const int wv   = threadIdx.x >> 6;
  const int row  = blockIdx.x * 4 + wv;
  if (row >= nrows) return;

  const float sgn1  = (lane & 1)  ? -1.0f : 1.0f;
  const float sgn2  = (lane & 2)  ? -1.0f : 1.0f;
  const float sgn4  = (lane & 4)  ? -1.0f : 1.0f;
  const float sgn8  = (lane & 8)  ? -1.0f : 1.0f;
  const float sgn16 = (lane & 16) ? -1.0f : 1.0f;
  const float sgn32 = (lane & 32) ? -1.0f : 1.0f;

  const float4* __restrict__ xr = (const float4*)(x + (size_t)row * DIM);
  const uint4*  __restrict__ s0 = (const uint4*)signs;
  const uint4*  __restrict__ s1 = (const uint4*)(signs + DIM);

  float4 v[8];
  #pragma unroll
  for (int c = 0; c < 8; ++c) {
    v[c] = xr[c * 64 + lane];
    v[c] = sign_flip(v[c], s0[c * 64 + lane]);
  }

  // ---- pass 1: bits 0..10, all in place ----
  #pragma unroll
  for (int c = 0; c < 8; ++c) bf_comps(v[c]);
  dpp_stage<0xB1>(v, sgn1);
  dpp_stage<0x4E>(v, sgn2);
  swz_stage<0x101F>(v, sgn4);
  swz_stage<0x201F>(v, sgn8);
  swz_stage<0x401F>(v, sgn16);
  pl32_stage(v, sgn32);
  bf_oct(v);

  // ---- pass 2: sign flip (natural layout), then bits 0..10 again ----
  #pragma unroll
  for (int c = 0; c < 8; ++c) v[c] = sign_flip(v[c], s1[c * 64 + lane]);

  #pragma unroll
  for (int c = 0; c < 8; ++c) bf_comps(v[c]);
  dpp_stage<0xB1>(v, sgn1);
  dpp_stage<0x4E>(v, sgn2);
  swz_stage<0x101F>(v, sgn4);
  swz_stage<0x201F>(v, sgn8);
  swz_stage<0x401F>(v, sgn16);
  pl32_stage(v, sgn32);
  bf_oct(v);

  // ---- scale (exact pow2) and naturally coalesced store ----
  const float sc = 1.0f / 2048.0f;
  float4* __restrict__ orow = (float4*)(out + (size_t)row * DIM);
  #pragma unroll
  for (int c = 0; c < 8; ++c) {
    float4 t = v[c];
    t.x *= sc; t.y *= sc; t.z *= sc; t.w *= sc;
    orow[c * 64 + lane] = t;
  }
}

extern "C" void kernel_launch(void* const* d_in, const int* in_sizes, int n_in,
                              void* d_out, int out_size, void* d_ws, size_t ws_size,
                              hipStream_t stream) {
  const float* x     = (const float*)d_in[0];
  const int*   signs = (const int*)d_in[1];
  float*       out   = (float*)d_out;
  const int nrows   = in_sizes[0] / DIM;   // 16384
  const int nblocks = nrows / 4;           // 4 waves (rows) per block
  hipLaunchKernelGGL(srht2_kernel, dim3(nblocks), dim3(256), 0, stream,
                     x, signs, out, nrows);
}

// Round 4
// 239.151 us; speedup vs baseline: 1.1111x; 1.1111x over previous
//
#include <hip/hip_runtime.h>

#define DIM 2048

typedef unsigned int uint2v __attribute__((ext_vector_type(2)));

// Exact sign flip: signs are +/-1 int32; -1 has the int sign bit set.
__device__ __forceinline__ float4 sign_flip(float4 v, uint4 s) {
  float4 r;
  r.x = __uint_as_float(__float_as_uint(v.x) ^ (s.x & 0x80000000u));
  r.y = __uint_as_float(__float_as_uint(v.y) ^ (s.y & 0x80000000u));
  r.z = __uint_as_float(__float_as_uint(v.z) ^ (s.z & 0x80000000u));
  r.w = __uint_as_float(__float_as_uint(v.w) ^ (s.w & 0x80000000u));
  return r;
}

#define BFLY(a, b) { float _t = (a); (a) = _t + (b); (b) = _t - (b); }

__device__ __forceinline__ void bf4_pair(float4 &a, float4 &b) {
  BFLY(a.x, b.x); BFLY(a.y, b.y); BFLY(a.z, b.z); BFLY(a.w, b.w);
}

// Butterfly element-index bits 0 and 1 (within the float4 components).
__device__ __forceinline__ void bf_comps(float4 &a) {
  BFLY(a.x, a.y); BFLY(a.z, a.w);   // bit 0
  BFLY(a.x, a.z); BFLY(a.y, a.w);   // bit 1
}

// Butterfly the 3 bits of the 8-register index (strides 1,2,4).
__device__ __forceinline__ void bf_oct(float4 v[8]) {
  bf4_pair(v[0], v[1]); bf4_pair(v[2], v[3]);
  bf4_pair(v[4], v[5]); bf4_pair(v[6], v[7]);
  bf4_pair(v[0], v[2]); bf4_pair(v[1], v[3]);
  bf4_pair(v[4], v[6]); bf4_pair(v[5], v[7]);
  bf4_pair(v[0], v[4]); bf4_pair(v[1], v[5]);
  bf4_pair(v[2], v[6]); bf4_pair(v[3], v[7]);
}

// Cross-lane butterfly on lane bit 0 / 1 via DPP quad_perm (VALU rate).
// 0xB1 = [1,0,3,2] (xor1), 0x4E = [2,3,0,1] (xor2).
template <int CTRL>
__device__ __forceinline__ float dpp_mov(float x) {
  return __int_as_float(
      __builtin_amdgcn_mov_dpp(__float_as_int(x), CTRL, 0xF, 0xF, true));
}

// Cross-lane data movement on lane bits 2..4 via ds_swizzle bit-mode xor.
// Pattern = (xor<<10) | (0x1F and-mask): pure lane^xor within 32-lane
// groups. Uses the DS crossbar only — no LDS storage, no bank conflicts,
// no barriers; lgkmcnt dependencies are tracked by the compiler.
template <int PAT>
__device__ __forceinline__ float swz_mov(float x) {
  return __int_as_float(__builtin_amdgcn_ds_swizzle(__float_as_int(x), PAT));
}

// ---- per-float4 butterfly stages (register-major: keeps peak liveness
// at v[8] + ONE register's 4 partner temps, so the allocator never needs
// more than ~44 VGPRs and never spills) ----

template <int CTRL>
__device__ __forceinline__ void dpp_stage1(float4 &a, float sgn) {
  float px = dpp_mov<CTRL>(a.x);
  float py = dpp_mov<CTRL>(a.y);
  float pz = dpp_mov<CTRL>(a.z);
  float pw = dpp_mov<CTRL>(a.w);
  // lane with bit clear: x + partner ; lane with bit set: partner - x
  a.x = fmaf(sgn, a.x, px);
  a.y = fmaf(sgn, a.y, py);
  a.z = fmaf(sgn, a.z, pz);
  a.w = fmaf(sgn, a.w, pw);
}

template <int PAT>
__device__ __forceinline__ void swz_stage1(float4 &a, float sgn) {
  float px = swz_mov<PAT>(a.x);
  float py = swz_mov<PAT>(a.y);
  float pz = swz_mov<PAT>(a.z);
  float pw = swz_mov<PAT>(a.w);
  a.x = fmaf(sgn, a.x, px);
  a.y = fmaf(sgn, a.y, py);
  a.z = fmaf(sgn, a.z, pz);
  a.w = fmaf(sgn, a.w, pw);
}

// Cross-lane butterfly on lane bit 5 via v_permlane32_swap_b32 (VALU rate).
// permlane32_swap(x, x) returns r[0] = x[lane & ~32] (lo half duplicated)
// and r[1] = x[lane | 32] (hi half duplicated).
__device__ __forceinline__ float pl32_bfly(float x, float sgn) {
  uint2v r = __builtin_amdgcn_permlane32_swap(
      __float_as_uint(x), __float_as_uint(x), false, false);
  // out = x[clear] + sgn * x[set]:
  //   lane<32: x[l] + x[l+32] ; lane>=32: x[l-32] - x[l]
  return fmaf(sgn, __uint_as_float(r[1]), __uint_as_float(r[0]));
}

__device__ __forceinline__ void pl32_stage1(float4 &a, float sgn) {
  a.x = pl32_bfly(a.x, sgn);
  a.y = pl32_bfly(a.y, sgn);
  a.z = pl32_bfly(a.z, sgn);
  a.w = pl32_bfly(a.w, sgn);
}

// All lane-local + cross-lane stages for one float4 (bits 0..7 of the
// element index). Each register runs its whole chain independently; the
// 8 chains give the scheduler ILP without inflating liveness.
__device__ __forceinline__ void lane_stages(float4 &a, float sgn1, float sgn2,
                                            float sgn4, float sgn8,
                                            float sgn16, float sgn32) {
  bf_comps(a);                  // bits 0,1 (comps)
  dpp_stage1<0xB1>(a, sgn1);    // bit 2 (lane^1)
  dpp_stage1<0x4E>(a, sgn2);    // bit 3 (lane^2)
  swz_stage1<0x101F>(a, sgn4);  // bit 4 (lane^4)
  swz_stage1<0x201F>(a, sgn8);  // bit 5 (lane^8)
  swz_stage1<0x401F>(a, sgn16); // bit 6 (lane^16)
  pl32_stage1(a, sgn32);        // bit 7 (lane^32)
}

// One wave per 2048-float row, everything in home position — NO LDS,
// NO barriers, NO transposes. Element index e = c*256 + lane*4 + comp:
//   bits 0-1: float4 comps, bits 2-7: lane bits, bits 8-10: reg index c.
// FWHT stages act on disjoint tensor factors, so any bit order is exact.
__global__ __launch_bounds__(256) void srht2_kernel(
    const float* __restrict__ x, const int* __restrict__ signs,
    float* __restrict__ out, int nrows) {
  const int lane = threadIdx.x & 63;
  const int wv   = threadIdx.x >> 6;
  const int row  = blockIdx.x * 4 + wv;
  if (row >= nrows) return;

  const float sgn1  = (lane & 1)  ? -1.0f : 1.0f;
  const float sgn2  = (lane & 2)  ? -1.0f : 1.0f;
  const float sgn4  = (lane & 4)  ? -1.0f : 1.0f;
  const float sgn8  = (lane & 8)  ? -1.0f : 1.0f;
  const float sgn16 = (lane & 16) ? -1.0f : 1.0f;
  const float sgn32 = (lane & 32) ? -1.0f : 1.0f;

  const float4* __restrict__ xr = (const float4*)(x + (size_t)row * DIM);
  const uint4*  __restrict__ s0 = (const uint4*)signs;
  const uint4*  __restrict__ s1 = (const uint4*)(signs + DIM);

  float4 v[8];
  #pragma unroll
  for (int c = 0; c < 8; ++c) v[c] = xr[c * 64 + lane];

  // ---- pass 1: sign flip + bits 0..7 per register, then bits 8..10 ----
  #pragma unroll
  for (int c = 0; c < 8; ++c) {
    v[c] = sign_flip(v[c], s0[c * 64 + lane]);
    lane_stages(v[c], sgn1, sgn2, sgn4, sgn8, sgn16, sgn32);
  }
  bf_oct(v);

  // ---- pass 2: sign flip (natural layout) + bits 0..7, then 8..10 ----
  #pragma unroll
  for (int c = 0; c < 8; ++c) {
    v[c] = sign_flip(v[c], s1[c * 64 + lane]);
    lane_stages(v[c], sgn1, sgn2, sgn4, sgn8, sgn16, sgn32);
  }
  bf_oct(v);

  // ---- scale (exact pow2) and naturally coalesced store ----
  const float sc = 1.0f / 2048.0f;
  float4* __restrict__ orow = (float4*)(out + (size_t)row * DIM);
  #pragma unroll
  for (int c = 0; c < 8; ++c) {
    float4 t = v[c];
    t.x *= sc; t.y *= sc; t.z *= sc; t.w *= sc;
    orow[c * 64 + lane] = t;
  }
}

extern "C" void kernel_launch(void* const* d_in, const int* in_sizes, int n_in,
                              void* d_out, int out_size, void* d_ws, size_t ws_size,
                              hipStream_t stream) {
  const float* x     = (const float*)d_in[0];
  const int*   signs = (const int*)d_in[1];
  float*       out   = (float*)d_out;
  const int nrows   = in_sizes[0] / DIM;   // 16384
  const int nblocks = nrows / 4;           // 4 waves (rows) per block
  hipLaunchKernelGGL(srht2_kernel, dim3(nblocks), dim3(256), 0, stream,
                     x, signs, out, nrows);
}